// Round 1
// baseline (36.276 us; speedup 1.0000x reference)
//
#include <hip/hip_runtime.h>

#define N_W   8192
#define N_E   32
#define N_NUC 8
#define D_H   32
#define NPAIR 496          // 32*31/2
#define NTAB  4096
#define TAB_INVH 256.0f    // table step = 1/256, range [0, 16)
#define TAB_H    (1.0f/256.0f)
#define WPB   8            // walkers per block

__device__ __forceinline__ float fast_rcp(float x) { return __builtin_amdgcn_rcpf(x); }
__device__ __forceinline__ float silu_f(float v)   { return v * fast_rcp(1.0f + __expf(-v)); }

// ---------------- Pre-kernel: tabulate scale_ee * MLP_ee(r) on [0,16) ----------------
__global__ void build_ee_table(const float* __restrict__ W1, const float* __restrict__ b1,
                               const float* __restrict__ W2, const float* __restrict__ b2,
                               const float* __restrict__ W3, const float* __restrict__ b3,
                               const float* __restrict__ scale_ee, float* __restrict__ table)
{
    int i = blockIdx.x * blockDim.x + threadIdx.x;
    if (i >= NTAB) return;
    float r = (float)i * TAB_H;
    float h1[D_H];
#pragma unroll
    for (int j = 0; j < D_H; ++j) h1[j] = silu_f(r * W1[j] + b1[j]);
    float out = b3[0];
#pragma unroll
    for (int j = 0; j < D_H; ++j) {
        float a = b2[j];
#pragma unroll
        for (int k = 0; k < D_H; ++k) a += h1[k] * W2[k * D_H + j];
        out += silu_f(a) * W3[j];
    }
    table[i] = scale_ee[0] * out;
}

// ---------------- Main kernel: 8 walkers / block, 1 thread = 1 electron ----------------
__launch_bounds__(256)
__global__ void jastrow_kernel(const float* __restrict__ re, const float* __restrict__ rnuc,
                               const float* __restrict__ charges, const int* __restrict__ mask,
                               const float* __restrict__ b_en, const float* __restrict__ b_ee,
                               const float* __restrict__ W1, const float* __restrict__ b1,
                               const float* __restrict__ W2, const float* __restrict__ b2,
                               const float* __restrict__ W3, const float* __restrict__ b3,
                               const float* __restrict__ scale_en, const float* __restrict__ table,
                               float* __restrict__ out)
{
    __shared__ __align__(16) float sW2[D_H * D_H];
    __shared__ __align__(16) float sW1[N_NUC * D_H];
    __shared__ __align__(16) float sb1[D_H], sb2[D_H], sW3[D_H];
    __shared__ __align__(16) float sTab[NTAB];
    __shared__ float sC[WPB][N_E][3];
    __shared__ float sNuc[N_NUC][3];
    __shared__ float sQ[N_NUC], sBs[N_NUC];
    __shared__ unsigned char sI[NPAIR], sJ[NPAIR];
    __shared__ float sA[NPAIR];

    const int tid = threadIdx.x;

    // stage weights / constants
    for (int idx = tid; idx < D_H * D_H; idx += 256) sW2[idx] = W2[idx];
    for (int idx = tid; idx < N_NUC * D_H; idx += 256) sW1[idx] = W1[idx];
    if (tid < D_H) { sb1[tid] = b1[tid]; sb2[tid] = b2[tid]; sW3[tid] = W3[tid]; }
    if (tid < N_NUC) {
        sNuc[tid][0] = rnuc[tid * 3 + 0];
        sNuc[tid][1] = rnuc[tid * 3 + 1];
        sNuc[tid][2] = rnuc[tid * 3 + 2];
        sQ[tid]  = charges[tid];
        sBs[tid] = logf(1.0f + __expf(b_en[tid]));   // softplus
    }
    {   // stage ee table (vectorized)
        const float4* tg = (const float4*)table;
        float4* ts = (float4*)sTab;
        for (int idx = tid; idx < NTAB / 4; idx += 256) ts[idx] = tg[idx];
    }
    // pair LUT: p -> (i,j), a coefficient
    for (int p = tid; p < NPAIR; p += 256) {
        int i = 0, start = 0;
        while (start + (N_E - 1 - i) <= p) { start += N_E - 1 - i; ++i; }
        int j = i + 1 + (p - start);
        sI[p] = (unsigned char)i;
        sJ[p] = (unsigned char)j;
        sA[p] = mask[i * N_E + j] ? 0.25f : 0.5f;
    }

    const int v = tid >> 5;       // walker slot in block
    const int l = tid & 31;       // electron index
    const int w = blockIdx.x * WPB + v;
    const float* rp = re + ((size_t)w * N_E + l) * 3;
    float ex = rp[0], ey = rp[1], ez = rp[2];
    sC[v][l][0] = ex; sC[v][l][1] = ey; sC[v][l][2] = ez;
    __syncthreads();

    float acc = 0.0f;

    // ---- e-n: cusp + squared distances ----
    float x[N_NUC];
#pragma unroll
    for (int n = 0; n < N_NUC; ++n) {
        float dx = ex - sNuc[n][0], dy = ey - sNuc[n][1], dz = ez - sNuc[n][2];
        float r2 = dx * dx + dy * dy + dz * dz;
        x[n] = r2;
        float r = sqrtf(r2);
        acc -= sQ[n] * r * fast_rcp(1.0f + sBs[n] * r);
    }

    // ---- e-n MLP: 8 -> 32 -> 32 -> 1 ----
    float h[D_H];
#pragma unroll
    for (int j = 0; j < D_H; ++j) h[j] = sb1[j];
#pragma unroll
    for (int k = 0; k < N_NUC; ++k) {
        float xk = x[k];
        const float4* row = (const float4*)(sW1 + k * D_H);
#pragma unroll
        for (int jq = 0; jq < D_H / 4; ++jq) {
            float4 wv = row[jq];
            h[jq * 4 + 0] += xk * wv.x;
            h[jq * 4 + 1] += xk * wv.y;
            h[jq * 4 + 2] += xk * wv.z;
            h[jq * 4 + 3] += xk * wv.w;
        }
    }
#pragma unroll
    for (int j = 0; j < D_H; ++j) h[j] = silu_f(h[j]);

    float g[D_H];
#pragma unroll
    for (int j = 0; j < D_H; ++j) g[j] = sb2[j];
#pragma unroll
    for (int k = 0; k < D_H; ++k) {
        float hk = h[k];
        const float4* row = (const float4*)(sW2 + k * D_H);
#pragma unroll
        for (int jq = 0; jq < D_H / 4; ++jq) {
            float4 wv = row[jq];
            g[jq * 4 + 0] += hk * wv.x;
            g[jq * 4 + 1] += hk * wv.y;
            g[jq * 4 + 2] += hk * wv.z;
            g[jq * 4 + 3] += hk * wv.w;
        }
    }
    float o = b3[0];
    {
        const float4* w3v = (const float4*)sW3;
#pragma unroll
        for (int jq = 0; jq < D_H / 4; ++jq) {
            float4 wv = w3v[jq];
            o += silu_f(g[jq * 4 + 0]) * wv.x;
            o += silu_f(g[jq * 4 + 1]) * wv.y;
            o += silu_f(g[jq * 4 + 2]) * wv.z;
            o += silu_f(g[jq * 4 + 3]) * wv.w;
        }
    }
    acc += scale_en[0] * o;

    // ---- e-e: cusp + table-interpolated MLP ----
    float bs = logf(1.0f + __expf(b_ee[0]));   // softplus(b_ee)
    for (int p = l; p < NPAIR; p += N_E) {
        int i = sI[p], j = sJ[p];
        float dx = sC[v][i][0] - sC[v][j][0];
        float dy = sC[v][i][1] - sC[v][j][1];
        float dz = sC[v][i][2] - sC[v][j][2];
        float r = sqrtf(dx * dx + dy * dy + dz * dz);
        acc += sA[p] * r * fast_rcp(1.0f + bs * r);
        float t = r * TAB_INVH;
        int i0 = (int)t;
        if (i0 > NTAB - 2) i0 = NTAB - 2;
        float f = t - (float)i0;
        float t0 = sTab[i0], t1 = sTab[i0 + 1];
        acc += t0 + f * (t1 - t0);
    }

    // ---- reduce 32 lanes (one walker) ----
#pragma unroll
    for (int m = 16; m; m >>= 1) acc += __shfl_xor(acc, m, 32);
    if (l == 0) out[w] = acc;
}

extern "C" void kernel_launch(void* const* d_in, const int* in_sizes, int n_in,
                              void* d_out, int out_size, void* d_ws, size_t ws_size,
                              hipStream_t stream)
{
    const float* re       = (const float*)d_in[0];
    const float* rnuc     = (const float*)d_in[1];
    const float* charges  = (const float*)d_in[2];
    const int*   mask     = (const int*)d_in[3];
    const float* b_en     = (const float*)d_in[4];
    const float* b_ee     = (const float*)d_in[5];
    const float* W1_en    = (const float*)d_in[6];
    const float* b1_en    = (const float*)d_in[7];
    const float* W2_en    = (const float*)d_in[8];
    const float* b2_en    = (const float*)d_in[9];
    const float* W3_en    = (const float*)d_in[10];
    const float* b3_en    = (const float*)d_in[11];
    const float* W1_ee    = (const float*)d_in[12];
    const float* b1_ee    = (const float*)d_in[13];
    const float* W2_ee    = (const float*)d_in[14];
    const float* b2_ee    = (const float*)d_in[15];
    const float* W3_ee    = (const float*)d_in[16];
    const float* b3_ee    = (const float*)d_in[17];
    const float* scale_en = (const float*)d_in[18];
    const float* scale_ee = (const float*)d_in[19];

    float* out   = (float*)d_out;
    float* table = (float*)d_ws;   // NTAB floats = 16 KB

    build_ee_table<<<NTAB / 256, 256, 0, stream>>>(W1_ee, b1_ee, W2_ee, b2_ee,
                                                   W3_ee, b3_ee, scale_ee, table);
    jastrow_kernel<<<N_W / WPB, 256, 0, stream>>>(re, rnuc, charges, mask,
                                                  b_en, b_ee,
                                                  W1_en, b1_en, W2_en, b2_en, W3_en, b3_en,
                                                  scale_en, table, out);
}

// Round 2
// 32.296 us; speedup vs baseline: 1.1232x; 1.1232x over previous
//
#include <hip/hip_runtime.h>

#define N_W   8192
#define N_E   32
#define N_NUC 8
#define D_H   32
#define NTAB  4096
#define TAB_INVH 256.0f    // table step = 1/256, range [0, 16)
#define TAB_H    (1.0f/256.0f)
#define WPB   8            // walkers per block

__device__ __forceinline__ float fast_rcp(float x) { return __builtin_amdgcn_rcpf(x); }
__device__ __forceinline__ float silu_f(float v)   { return v * fast_rcp(1.0f + __expf(-v)); }

// ---------------- Pre-kernel: tabulate scale_ee * MLP_ee(r) on [0,16) ----------------
// One table entry per 32-lane group; lane j owns hidden unit j of layer 2.
__global__ void build_ee_table(const float* __restrict__ W1, const float* __restrict__ b1,
                               const float* __restrict__ W2, const float* __restrict__ b2,
                               const float* __restrict__ W3, const float* __restrict__ b3,
                               const float* __restrict__ scale_ee, float* __restrict__ table)
{
    const int tid   = threadIdx.x;
    const int j     = tid & 31;                    // hidden unit (layer 2)
    const int entry = blockIdx.x * 8 + (tid >> 5); // table index
    const float r   = (float)entry * TAB_H;

    float g = b2[j];
#pragma unroll
    for (int k = 0; k < D_H; ++k) {
        float hk = silu_f(r * W1[k] + b1[k]);      // layer 1 (input dim = 1)
        g += hk * W2[k * D_H + j];
    }
    float o = silu_f(g) * W3[j];
#pragma unroll
    for (int m = 16; m; m >>= 1) o += __shfl_xor(o, m, 32);
    if (j == 0) table[entry] = scale_ee[0] * (o + b3[0]);
}

// ---------------- Main kernel: 8 walkers / block, 1 thread = 1 electron ----------------
// All weights/biases/nuclei read via wave-uniform scalar loads (constant cache),
// keeping the LDS pipe free for the table + partner-coordinate reads.
__launch_bounds__(256, 4)
__global__ void jastrow_kernel(const float* __restrict__ re, const float* __restrict__ rnuc,
                               const float* __restrict__ charges, const int* __restrict__ mask,
                               const float* __restrict__ b_en, const float* __restrict__ b_ee,
                               const float* __restrict__ W1, const float* __restrict__ b1,
                               const float* __restrict__ W2, const float* __restrict__ b2,
                               const float* __restrict__ W3, const float* __restrict__ b3,
                               const float* __restrict__ scale_en, const float* __restrict__ table,
                               float* __restrict__ out)
{
    __shared__ __align__(16) float sTab[NTAB];     // 16 KB
    __shared__ float4 sC4[WPB][N_E];               // 4 KB, padded coords
    __shared__ float  sA2[16][N_E];                // 2 KB, a-coef per (d, lane)

    const int tid = threadIdx.x;

    {   // stage ee table (vectorized)
        const float4* tg = (const float4*)table;
        float4* ts = (float4*)sTab;
        for (int idx = tid; idx < NTAB / 4; idx += 256) ts[idx] = tg[idx];
    }
    // rotation-pair a-coefficients: pair (l, (l+d)&31), a = mask[min][max] ? 0.25 : 0.5
    for (int idx = tid; idx < 16 * N_E; idx += 256) {
        int d = (idx >> 5) + 1, l0 = idx & 31;
        int j = (l0 + d) & 31;
        int a = l0 < j ? l0 : j, b = l0 < j ? j : l0;
        sA2[d - 1][l0] = mask[a * N_E + b] ? 0.25f : 0.5f;
    }

    const int v = tid >> 5;       // walker slot in block
    const int l = tid & 31;       // electron index
    const int w = blockIdx.x * WPB + v;
    const float* rp = re + ((size_t)w * N_E + l) * 3;
    float ex = rp[0], ey = rp[1], ez = rp[2];
    sC4[v][l] = make_float4(ex, ey, ez, 0.0f);
    __syncthreads();

    float acc = 0.0f;

    // ---- e-n: cusp + squared distances (nuclei/charges scalar-loaded) ----
    float x[N_NUC];
#pragma unroll
    for (int n = 0; n < N_NUC; ++n) {
        float dx = ex - rnuc[n * 3 + 0];
        float dy = ey - rnuc[n * 3 + 1];
        float dz = ez - rnuc[n * 3 + 2];
        float r2 = dx * dx + dy * dy + dz * dz;
        x[n] = r2;
        float r = sqrtf(r2);
        float bsn = __logf(1.0f + __expf(b_en[n]));      // softplus, uniform
        acc -= charges[n] * r * fast_rcp(1.0f + bsn * r);
    }

    // ---- e-n MLP: 8 -> 32 -> 32 -> 1, weights in SGPRs ----
    float h[D_H];
#pragma unroll
    for (int jj = 0; jj < D_H; ++jj) h[jj] = b1[jj];
#pragma unroll
    for (int k = 0; k < N_NUC; ++k) {
        float xk = x[k];
#pragma unroll
        for (int jj = 0; jj < D_H; ++jj) h[jj] += xk * W1[k * D_H + jj];
    }
#pragma unroll
    for (int jj = 0; jj < D_H; ++jj) h[jj] = silu_f(h[jj]);

    float g[D_H];
#pragma unroll
    for (int jj = 0; jj < D_H; ++jj) g[jj] = b2[jj];
#pragma unroll
    for (int k = 0; k < D_H; ++k) {
        float hk = h[k];
#pragma unroll
        for (int jj = 0; jj < D_H; ++jj) g[jj] += hk * W2[k * D_H + jj];
    }
    float o = b3[0];
#pragma unroll
    for (int jj = 0; jj < D_H; ++jj) o += silu_f(g[jj]) * W3[jj];
    acc += scale_en[0] * o;

    // ---- e-e: rotation enumeration, 16 distances per lane ----
    float bs = __logf(1.0f + __expf(b_ee[0]));   // softplus(b_ee)
#pragma unroll
    for (int d = 1; d <= 16; ++d) {
        int j = (l + d) & 31;
        float4 cj = sC4[v][j];
        float dx = ex - cj.x, dy = ey - cj.y, dz = ez - cj.z;
        float r = sqrtf(dx * dx + dy * dy + dz * dz);
        float c = sA2[d - 1][l] * r * fast_rcp(1.0f + bs * r);
        float t = r * TAB_INVH;
        int i0 = (int)t;
        if (i0 > NTAB - 2) i0 = NTAB - 2;
        float f = t - (float)i0;
        float t0 = sTab[i0], t1 = sTab[i0 + 1];
        float contrib = c + t0 + f * (t1 - t0);
        acc += (d == 16) ? 0.5f * contrib : contrib;   // d=16 pairs counted twice
    }

    // ---- reduce 32 lanes (one walker) ----
#pragma unroll
    for (int m = 16; m; m >>= 1) acc += __shfl_xor(acc, m, 32);
    if (l == 0) out[w] = acc;
}

extern "C" void kernel_launch(void* const* d_in, const int* in_sizes, int n_in,
                              void* d_out, int out_size, void* d_ws, size_t ws_size,
                              hipStream_t stream)
{
    const float* re       = (const float*)d_in[0];
    const float* rnuc     = (const float*)d_in[1];
    const float* charges  = (const float*)d_in[2];
    const int*   mask     = (const int*)d_in[3];
    const float* b_en     = (const float*)d_in[4];
    const float* b_ee     = (const float*)d_in[5];
    const float* W1_en    = (const float*)d_in[6];
    const float* b1_en    = (const float*)d_in[7];
    const float* W2_en    = (const float*)d_in[8];
    const float* b2_en    = (const float*)d_in[9];
    const float* W3_en    = (const float*)d_in[10];
    const float* b3_en    = (const float*)d_in[11];
    const float* W1_ee    = (const float*)d_in[12];
    const float* b1_ee    = (const float*)d_in[13];
    const float* W2_ee    = (const float*)d_in[14];
    const float* b2_ee    = (const float*)d_in[15];
    const float* W3_ee    = (const float*)d_in[16];
    const float* b3_ee    = (const float*)d_in[17];
    const float* scale_en = (const float*)d_in[18];
    const float* scale_ee = (const float*)d_in[19];

    float* out   = (float*)d_out;
    float* table = (float*)d_ws;   // NTAB floats = 16 KB

    build_ee_table<<<NTAB / 8, 256, 0, stream>>>(W1_ee, b1_ee, W2_ee, b2_ee,
                                                 W3_ee, b3_ee, scale_ee, table);
    jastrow_kernel<<<N_W / WPB, 256, 0, stream>>>(re, rnuc, charges, mask,
                                                  b_en, b_ee,
                                                  W1_en, b1_en, W2_en, b2_en, W3_en, b3_en,
                                                  scale_en, table, out);
}

// Round 3
// 30.788 us; speedup vs baseline: 1.1782x; 1.0490x over previous
//
#include <hip/hip_runtime.h>

#define N_W   8192
#define N_E   32
#define N_NUC 8
#define D_H   32
#define NTAB  4096
#define TAB_INVH 256.0f    // table step = 1/256, range [0, 16)
#define TAB_H    (1.0f/256.0f)
#define WPB   8            // walkers per block

__device__ __forceinline__ float fast_rcp(float x) { return __builtin_amdgcn_rcpf(x); }
__device__ __forceinline__ float silu_f(float v)   { return v * fast_rcp(1.0f + __expf(-v)); }

// ---------------- Pre-kernel: tabulate scale_ee * MLP_ee(r) on [0,16) ----------------
// One table entry per 32-lane group; lane j owns hidden unit j of layer 2.
// Block 0 additionally writes softplus(b_en[0..7]) and softplus(b_ee) to aux.
__global__ void build_ee_table(const float* __restrict__ W1, const float* __restrict__ b1,
                               const float* __restrict__ W2, const float* __restrict__ b2,
                               const float* __restrict__ W3, const float* __restrict__ b3,
                               const float* __restrict__ scale_ee,
                               const float* __restrict__ b_en, const float* __restrict__ b_ee,
                               float* __restrict__ table, float* __restrict__ aux)
{
    const int tid   = threadIdx.x;
    if (blockIdx.x == 0) {
        if (tid < N_NUC) aux[tid] = __logf(1.0f + __expf(b_en[tid]));
        if (tid == N_NUC) aux[tid] = __logf(1.0f + __expf(b_ee[0]));
    }
    const int j     = tid & 31;                    // hidden unit (layer 2)
    const int entry = blockIdx.x * 8 + (tid >> 5); // table index
    const float r   = (float)entry * TAB_H;

    float g = b2[j];
#pragma unroll
    for (int k = 0; k < D_H; ++k) {
        float hk = silu_f(r * W1[k] + b1[k]);      // layer 1 (input dim = 1)
        g += hk * W2[k * D_H + j];
    }
    float o = silu_f(g) * W3[j];
#pragma unroll
    for (int m = 16; m; m >>= 1) o += __shfl_xor(o, m, 32);
    if (j == 0) table[entry] = scale_ee[0] * (o + b3[0]);
}

// ---------------- Main kernel: 8 walkers / block, 1 thread = 1 electron ----------------
// Weights via wave-uniform scalar loads; MLP math in float2 so the compiler emits
// v_pk_fma_f32 (packed fp32, 2 FMA/instr — the only path to the 157 TF fp32 rate).
__launch_bounds__(256, 4)
__global__ void jastrow_kernel(const float* __restrict__ re, const float* __restrict__ rnuc,
                               const float* __restrict__ charges, const int* __restrict__ mask,
                               const float* __restrict__ W1, const float* __restrict__ b1,
                               const float* __restrict__ W2, const float* __restrict__ b2,
                               const float* __restrict__ W3, const float* __restrict__ b3,
                               const float* __restrict__ scale_en, const float* __restrict__ table,
                               const float* __restrict__ aux,
                               float* __restrict__ out)
{
    __shared__ __align__(16) float sTab[NTAB];     // 16 KB
    __shared__ float4 sC4[WPB][N_E];               // 4 KB, padded coords
    __shared__ float  sA2[16][N_E];                // 2 KB, a-coef per (d, lane)

    const int tid = threadIdx.x;

    {   // stage ee table (vectorized)
        const float4* tg = (const float4*)table;
        float4* ts = (float4*)sTab;
        for (int idx = tid; idx < NTAB / 4; idx += 256) ts[idx] = tg[idx];
    }
    // rotation-pair a-coefficients: pair (l, (l+d)&31), a = mask[min][max] ? 0.25 : 0.5
    for (int idx = tid; idx < 16 * N_E; idx += 256) {
        int d = (idx >> 5) + 1, l0 = idx & 31;
        int j = (l0 + d) & 31;
        int a = l0 < j ? l0 : j, b = l0 < j ? j : l0;
        sA2[d - 1][l0] = mask[a * N_E + b] ? 0.25f : 0.5f;
    }

    const int v = tid >> 5;       // walker slot in block
    const int l = tid & 31;       // electron index
    const int w = blockIdx.x * WPB + v;
    const float* rp = re + ((size_t)w * N_E + l) * 3;
    float ex = rp[0], ey = rp[1], ez = rp[2];
    sC4[v][l] = make_float4(ex, ey, ez, 0.0f);
    __syncthreads();

    float acc = 0.0f;

    // ---- e-n: cusp + squared distances (softplus(b_en) precomputed in aux) ----
    float x[N_NUC];
#pragma unroll
    for (int n = 0; n < N_NUC; ++n) {
        float dx = ex - rnuc[n * 3 + 0];
        float dy = ey - rnuc[n * 3 + 1];
        float dz = ez - rnuc[n * 3 + 2];
        float r2 = dx * dx + dy * dy + dz * dz;
        x[n] = r2;
        float r = sqrtf(r2);
        acc -= charges[n] * r * fast_rcp(1.0f + aux[n] * r);
    }

    // ---- e-n MLP layer 1: 8 -> 32, packed fp32 ----
    float2 h2[D_H / 2];
#pragma unroll
    for (int jj = 0; jj < D_H / 2; ++jj) h2[jj] = ((const float2*)b1)[jj];
#pragma unroll
    for (int k = 0; k < N_NUC; ++k) {
        float xk = x[k];
        const float2* row = (const float2*)(W1 + k * D_H);
#pragma unroll
        for (int jj = 0; jj < D_H / 2; ++jj) {
            float2 wv = row[jj];
            h2[jj].x = fmaf(xk, wv.x, h2[jj].x);
            h2[jj].y = fmaf(xk, wv.y, h2[jj].y);
        }
    }
    float h[D_H];
#pragma unroll
    for (int jj = 0; jj < D_H / 2; ++jj) {
        h[2 * jj + 0] = silu_f(h2[jj].x);
        h[2 * jj + 1] = silu_f(h2[jj].y);
    }

    // ---- layer 2: 32 -> 32 in two 16-wide halves (caps VGPR), packed fp32 ----
    float o = b3[0];
#pragma unroll
    for (int half = 0; half < 2; ++half) {
        float2 g2[8];
#pragma unroll
        for (int jj = 0; jj < 8; ++jj) g2[jj] = ((const float2*)b2)[half * 8 + jj];
#pragma unroll
        for (int k = 0; k < D_H; ++k) {
            float hk = h[k];
            const float2* row = (const float2*)(W2 + k * D_H + half * 16);
#pragma unroll
            for (int jj = 0; jj < 8; ++jj) {
                float2 wv = row[jj];
                g2[jj].x = fmaf(hk, wv.x, g2[jj].x);
                g2[jj].y = fmaf(hk, wv.y, g2[jj].y);
            }
        }
#pragma unroll
        for (int jj = 0; jj < 8; ++jj) {
            o += silu_f(g2[jj].x) * W3[half * 16 + 2 * jj + 0];
            o += silu_f(g2[jj].y) * W3[half * 16 + 2 * jj + 1];
        }
    }
    acc += scale_en[0] * o;

    // ---- e-e: rotation enumeration, 16 distances per lane ----
    float bs = aux[N_NUC];   // softplus(b_ee), precomputed
#pragma unroll
    for (int d = 1; d <= 16; ++d) {
        int j = (l + d) & 31;
        float4 cj = sC4[v][j];
        float dx = ex - cj.x, dy = ey - cj.y, dz = ez - cj.z;
        float r = sqrtf(dx * dx + dy * dy + dz * dz);
        float c = sA2[d - 1][l] * r * fast_rcp(1.0f + bs * r);
        float t = r * TAB_INVH;
        int i0 = (int)t;
        if (i0 > NTAB - 2) i0 = NTAB - 2;
        float f = t - (float)i0;
        float t0 = sTab[i0], t1 = sTab[i0 + 1];
        float contrib = c + t0 + f * (t1 - t0);
        acc += (d == 16) ? 0.5f * contrib : contrib;   // d=16 pairs counted twice
    }

    // ---- reduce 32 lanes (one walker) ----
#pragma unroll
    for (int m = 16; m; m >>= 1) acc += __shfl_xor(acc, m, 32);
    if (l == 0) out[w] = acc;
}

extern "C" void kernel_launch(void* const* d_in, const int* in_sizes, int n_in,
                              void* d_out, int out_size, void* d_ws, size_t ws_size,
                              hipStream_t stream)
{
    const float* re       = (const float*)d_in[0];
    const float* rnuc     = (const float*)d_in[1];
    const float* charges  = (const float*)d_in[2];
    const int*   mask     = (const int*)d_in[3];
    const float* b_en     = (const float*)d_in[4];
    const float* b_ee     = (const float*)d_in[5];
    const float* W1_en    = (const float*)d_in[6];
    const float* b1_en    = (const float*)d_in[7];
    const float* W2_en    = (const float*)d_in[8];
    const float* b2_en    = (const float*)d_in[9];
    const float* W3_en    = (const float*)d_in[10];
    const float* b3_en    = (const float*)d_in[11];
    const float* W1_ee    = (const float*)d_in[12];
    const float* b1_ee    = (const float*)d_in[13];
    const float* W2_ee    = (const float*)d_in[14];
    const float* b2_ee    = (const float*)d_in[15];
    const float* W3_ee    = (const float*)d_in[16];
    const float* b3_ee    = (const float*)d_in[17];
    const float* scale_en = (const float*)d_in[18];
    const float* scale_ee = (const float*)d_in[19];

    float* out   = (float*)d_out;
    float* table = (float*)d_ws;          // NTAB floats = 16 KB
    float* aux   = table + NTAB;          // softplus(b_en[0..7]), softplus(b_ee)

    build_ee_table<<<NTAB / 8, 256, 0, stream>>>(W1_ee, b1_ee, W2_ee, b2_ee,
                                                 W3_ee, b3_ee, scale_ee,
                                                 b_en, b_ee, table, aux);
    jastrow_kernel<<<N_W / WPB, 256, 0, stream>>>(re, rnuc, charges, mask,
                                                  W1_en, b1_en, W2_en, b2_en, W3_en, b3_en,
                                                  scale_en, table, aux, out);
}